// Round 9
// baseline (227.977 us; speedup 1.0000x reference)
//
#include <hip/hip_runtime.h>
#include <stdint.h>
#include <math.h>

// B=2 S=2048 E=1024 H=16 DH=64 ROT=32 CTX=2048
// d_in / d_out are FLOAT32 (per reference). Internals use bf16 MFMA.
typedef __bf16 bf16x8 __attribute__((ext_vector_type(8)));
typedef float f32x4 __attribute__((ext_vector_type(4)));

__device__ __forceinline__ float bf2f(uint16_t x) {
  unsigned u = ((unsigned)x) << 16;
  float f;
  __builtin_memcpy(&f, &u, 4);
  return f;
}
// native RTNE f32->bf16
__device__ __forceinline__ uint16_t f2bf(float f) {
  __bf16 h = (__bf16)f;
  uint16_t u;
  __builtin_memcpy(&u, &h, 2);
  return u;
}
// round two float4s to bf16x8
__device__ __forceinline__ bf16x8 pack8(float4 lo, float4 hi) {
  bf16x8 v;
  v[0] = (__bf16)lo.x; v[1] = (__bf16)lo.y; v[2] = (__bf16)lo.z; v[3] = (__bf16)lo.w;
  v[4] = (__bf16)hi.x; v[5] = (__bf16)hi.y; v[6] = (__bf16)hi.z; v[7] = (__bf16)hi.w;
  return v;
}
// load 8 contiguous f32, round to bf16x8
__device__ __forceinline__ bf16x8 cvt8(const float* p) {
  return pack8(*(const float4*)p, *(const float4*)(p + 4));
}

// direct global->LDS, 16B/lane; LDS dest = wave-uniform base + lane*16
typedef __attribute__((address_space(1))) const unsigned int gu32;
typedef __attribute__((address_space(3))) unsigned int lu32;
__device__ __forceinline__ void async_copy16(const void* gp, void* lp) {
  __builtin_amdgcn_global_load_lds((gu32*)gp, (lu32*)lp, 16, 0, 0);
}

// f32 -> bf16 elementwise convert; grid.z selects tensor, grid.x*256*8 = count
__global__ __launch_bounds__(256) void cvt_kernel(
    const float* __restrict__ s0, uint16_t* __restrict__ d0,
    const float* __restrict__ s1, uint16_t* __restrict__ d1,
    const float* __restrict__ s2, uint16_t* __restrict__ d2,
    const float* __restrict__ s3, uint16_t* __restrict__ d3) {
  const int z = blockIdx.z;
  const float* s = z == 0 ? s0 : z == 1 ? s1 : z == 2 ? s2 : s3;
  uint16_t* d = z == 0 ? d0 : z == 1 ? d1 : z == 2 ? d2 : d3;
  const size_t idx = ((size_t)blockIdx.x * 256 + threadIdx.x) * 8;
  *(bf16x8*)(d + idx) = cvt8(s + idx);
}

// NT GEMM + bias: C[m,n] = sum_k A[m,k]*W[n,k] + bias[n]
// BM x (NF*32) tile, BK=64, 256 threads as 2m x 2n waves, acc[BM/32][NF].
// R14: pure-bf16 both-operand global_load_lds path (A_F32=W_F32=false) is
// the m97-proven config: 0.25 KB staged / MFMA. 128x128 QKV tile = 32KB
// LDS = 5 blocks/CU, zero reg staging. A_F32/W_F32 reg-staged paths
// retained for the ws_size<64MB fallback.
// LDS XOR-swizzled: conflict-free and contiguous rows. m-fastest block map
// for XCD L2 locality. ROPE fused into bf16 epilogue for dh<32.
// VT: z==2 writes C^T per-head.
template <bool A_F32, bool W_F32, bool C_F32, bool VT, bool ROPE, int BM, int NF>
__global__ __launch_bounds__(256) void gemm3_kernel(
    const void* __restrict__ A0, const void* __restrict__ W0,
    const float* __restrict__ b0, void* __restrict__ C0,
    const void* __restrict__ A1, const void* __restrict__ W1,
    const float* __restrict__ b1, void* __restrict__ C1,
    const void* __restrict__ A2, const void* __restrict__ W2,
    const float* __restrict__ b2, void* __restrict__ C2,
    int M, int N, int K) {
  constexpr int BN = NF * 32;
  constexpr int AF = BM / 32;   // A frags per wave, also A staging iters
  const int z = blockIdx.z;
  const void* Av = z == 0 ? A0 : z == 1 ? A1 : A2;
  const void* Wp = z == 0 ? W0 : z == 1 ? W1 : W2;
  const float* bias = z == 0 ? b0 : z == 1 ? b1 : b2;
  void* Cv = z == 0 ? C0 : z == 1 ? C1 : C2;

  __shared__ __align__(16) uint16_t As[BM * 64];
  __shared__ __align__(16) uint16_t Bs[BN * 64];
  const int tid = threadIdx.x;
  const int wave = tid >> 6, lane = tid & 63;
  const int quad = lane >> 4, l16 = lane & 15;
  // XCD-locality swizzle: m fastest in HW dispatch order
  const int l = blockIdx.y * gridDim.x + blockIdx.x;
  const int nmt = M / BM;
  const int bm = (l % nmt) * BM;
  const int bn = (l / nmt) * BN;
  const int wm = (wave >> 1) * (BM / 2);
  const int wn = (wave & 1) * (BN / 2);

  f32x4 acc[AF][NF] = {};

  for (int k0 = 0; k0 < K; k0 += 64) {
    bf16x8 ar[AF], wr[NF];
    if (A_F32) {
#pragma unroll
      for (int i = 0; i < AF; i++) {
        const int c = i * 256 + tid;
        const int r = c >> 3, pc = ((c & 7) ^ (r & 7)) << 3;
        ar[i] = cvt8((const float*)Av + (size_t)(bm + r) * K + k0 + pc);
      }
    }
    if (W_F32) {
#pragma unroll
      for (int i = 0; i < NF; i++) {
        const int c = i * 256 + tid;
        const int r = c >> 3, pc = ((c & 7) ^ (r & 7)) << 3;
        wr[i] = cvt8((const float*)Wp + (size_t)(bn + r) * K + k0 + pc);
      }
    }
    if (k0) __syncthreads();
#pragma unroll
    for (int i = 0; i < AF; i++) {
      const int c = i * 256 + tid;
      const int r = c >> 3, pc = ((c & 7) ^ (r & 7)) << 3;
      if (A_F32) *(bf16x8*)(As + c * 8) = ar[i];
      else async_copy16((const uint16_t*)Av + (size_t)(bm + r) * K + k0 + pc,
                        As + (i * 256 + (tid & 192)) * 8);
    }
#pragma unroll
    for (int i = 0; i < NF; i++) {
      const int c = i * 256 + tid;
      const int r = c >> 3, pc = ((c & 7) ^ (r & 7)) << 3;
      if (W_F32) *(bf16x8*)(Bs + c * 8) = wr[i];
      else async_copy16((const uint16_t*)Wp + (size_t)(bn + r) * K + k0 + pc,
                        Bs + (i * 256 + (tid & 192)) * 8);
    }
    __syncthreads();
#pragma unroll
    for (int s = 0; s < 2; s++) {
      bf16x8 af[AF], bfr[NF];
#pragma unroll
      for (int i = 0; i < AF; i++) {
        const int Ra = wm + i * 16 + l16;
        af[i] = *(const bf16x8*)(As + Ra * 64 + (((s * 4 + quad) ^ (Ra & 7)) << 3));
      }
#pragma unroll
      for (int j = 0; j < NF; j++) {
        const int Rb = wn + j * 16 + l16;
        bfr[j] = *(const bf16x8*)(Bs + Rb * 64 + (((s * 4 + quad) ^ (Rb & 7)) << 3));
      }
#pragma unroll
      for (int i = 0; i < AF; i++)
#pragma unroll
        for (int j = 0; j < NF; j++)
          acc[i][j] = __builtin_amdgcn_mfma_f32_16x16x32_bf16(af[i], bfr[j], acc[i][j], 0, 0, 0);
    }
  }
  if (VT && z == 2) {
#pragma unroll
    for (int j = 0; j < NF; j++) {
      const int n = bn + wn + j * 16 + l16;
      const float bj = bias[n];
      const int h = n >> 6, dh = n & 63;
#pragma unroll
      for (int i = 0; i < AF; i++) {
        const int m0 = bm + wm + i * 16 + quad * 4;
        const int b = m0 >> 11, s0 = m0 & 2047;
        uint2 pk;
        pk.x = (unsigned)f2bf(acc[i][j][0] + bj) |
               ((unsigned)f2bf(acc[i][j][1] + bj) << 16);
        pk.y = (unsigned)f2bf(acc[i][j][2] + bj) |
               ((unsigned)f2bf(acc[i][j][3] + bj) << 16);
        *(uint2*)((uint16_t*)Cv + ((size_t)((b * 16 + h) * 64 + dh)) * 2048 + s0) = pk;
      }
    }
  } else {
#pragma unroll
    for (int j = 0; j < NF; j++) {
      const int n = bn + wn + j * 16 + l16;
      const float bj = bias[n];
      // dh = n & 63; rot iff dh<32 — wave-uniform: ((wn + j*16) & 63) < 32
      const int dh = (wn + j * 16 + l16) & 63;
      const bool rot = ROPE && (((wn + j * 16) & 63) < 32);
      float invrev = 0.f;
      if (rot)
        invrev = __expf(-0.5756462732485115f * (float)(dh >> 1)) *
                 0.15915494309189535f;  // 10000^(-i/16) / 2pi
#pragma unroll
      for (int i = 0; i < AF; i++) {
        const int m0 = bm + wm + i * 16 + quad * 4;
#pragma unroll
        for (int r = 0; r < 4; r++) {
          float v = acc[i][j][r] + bj;
          if (rot) {
            const int s_pos = (m0 + r) & 2047;
            float rev = (float)s_pos * invrev;
            rev -= floorf(rev);
            const float sn = __builtin_amdgcn_sinf(rev);
            const float cs = __builtin_amdgcn_cosf(rev);
            const float partner = __shfl_xor(v, 1);
            v = (dh & 1) ? (v * cs + partner * sn) : (v * cs - partner * sn);
          }
          if (C_F32) ((float*)Cv)[(size_t)(m0 + r) * N + n] = v;
          else       ((uint16_t*)Cv)[(size_t)(m0 + r) * N + n] = f2bf(v);
        }
      }
    }
  }
}

// Flash attention, causal, MAX-FREE softmax (scores statically bounded ->
// exp finite; masked lanes -1e30 -> exp=0). S^T form: lane l16 owns q-row
// l16; P pack = 4x ds_write_b64; one scalar row-sum per frag.
// R19 SPLIT-K: grid was 512 = a hard 2-blocks/CU cap (R8: balance fixed
// but occupancy stuck at 11.6% — the per-kt serial chain can't be hidden
// by 8 waves/CU). Splitting each q-tile's kt range in half doubles blocks
// to 1024 = 4/CU at CONSTANT total staged bytes (the R5 failure mode was
// smaller q-tiles doubling staging). Max-free softmax => partials combine
// LINEARLY: blocks write unnormalized o (f32) + row lsum; combine_kernel
// sums & normalizes. Work map: co-resident 4-set {s7,s7+32,s7+64,s7+96}
// alternates desc/asc qt2 -> every CU gets exactly 34 kt-halves.
// R19b: log2e folded into Q pre-scale (0.125*log2e) -> raw v_exp_f32
// (exp2) in softmax, no per-element mul. Mask -1e30 -> exp2 -> 0 still.
template <bool SPLIT>
__global__ __launch_bounds__(256) void flash_kernel(const uint16_t* __restrict__ Q,
                                                    const uint16_t* __restrict__ K,
                                                    const uint16_t* __restrict__ VT,
                                                    uint16_t* __restrict__ AO,
                                                    float* __restrict__ Po,
                                                    float* __restrict__ Pl) {
  const int bx = blockIdx.x;           // SPLIT: 1024 blocks; else 512
  const int xcd = bx & 7;
  int bh, qt2, half;
  if (SPLIT) {
    const int s7 = bx >> 3;            // 0..127 within XCD
    const int grp = s7 >> 5;           // 0..3 -> bh group
    const int w = s7 & 31;
    bh = grp * 8 + xcd;
    const int qb = w & 15;
    qt2 = (grp & 1) ? qb : 15 - qb;    // alternate direction per group
    half = w >> 4;
  } else {
    const int slot = bx >> 3;          // 0..63
    bh = (slot >> 4) * 8 + xcd;
    qt2 = (slot < 32) ? (15 - (slot & 15)) : (slot & 15);
    half = 0;
  }
  const int h = bh & 15;
  const int b = bh >> 4;
  const int tid = threadIdx.x;
  const int wave = tid >> 6, lane = tid & 63;
  const int quad = lane >> 4, l16 = lane & 15;

  __shared__ __align__(16) uint16_t Ks[64 * 64];      // [n][d] swizzled
  __shared__ __align__(16) uint16_t Vt[64 * 64];      // [d][n] swizzled
  __shared__ __align__(16) uint16_t Ps[4][32 * 72];   // per-wave P (2 frags)

  // Q fragments (B-operand layout: lane l16 = q-row); pre-scale folds
  // 1/sqrt(64) * log2(e) so softmax is a bare exp2.
  const float QS = 0.18033688011112042f;
  const int qrow0 = qt2 * 128 + wave * 16 + l16;      // frag0
  const int qrow1 = qrow0 + 64;                       // frag1
  bf16x8 qf0[2], qf1[2];
#pragma unroll
  for (int s = 0; s < 2; s++) {
    union { bf16x8 v; uint16_t u[8]; } t0, t1;
    t0.v = *(const bf16x8*)(Q + ((size_t)(b * 2048 + qrow0) * 1024) + h * 64 + s * 32 + quad * 8);
    t1.v = *(const bf16x8*)(Q + ((size_t)(b * 2048 + qrow1) * 1024) + h * 64 + s * 32 + quad * 8);
#pragma unroll
    for (int j = 0; j < 8; j++) {
      t0.u[j] = f2bf(bf2f(t0.u[j]) * QS);
      t1.u[j] = f2bf(bf2f(t1.u[j]) * QS);
    }
    qf0[s] = t0.v;
    qf1[s] = t1.v;
  }

  const size_t vbase = ((size_t)((b * 16 + h) * 64)) * 2048;  // VT head base

  float lsum0 = 0.f, lsum1 = 0.f;
  f32x4 o0[4] = {}, o1[4] = {};

  const int nkt = 2 * qt2 + 2;
  const int k0b = SPLIT ? half * (qt2 + 1) : 0;
  const int k0e = SPLIT ? (half + 1) * (qt2 + 1) : nkt;
  for (int kt = k0b; kt < k0e; kt++) {
    if (kt != k0b) __syncthreads();
#pragma unroll
    for (int i = 0; i < 2; i++) {
      const int c = i * 256 + tid;
      const int r = c >> 3, pc = ((c & 7) ^ (r & 7)) << 3;
      async_copy16(K + ((size_t)(b * 2048 + kt * 64 + r) * 1024) + h * 64 + pc,
                   Ks + (i * 256 + (tid & 192)) * 8);
      async_copy16(VT + vbase + (size_t)r * 2048 + kt * 64 + pc,
                   Vt + (i * 256 + (tid & 192)) * 8);
    }
    __syncthreads();

    const bool f0 = (kt < nkt - 1);  // low frag fully masked at last kt

    // ---- frag1 S^T ----
    {
      f32x4 sacc[4] = {};
#pragma unroll
      for (int s = 0; s < 2; s++)
#pragma unroll
        for (int t = 0; t < 4; t++) {
          const int R = t * 16 + l16;
          bf16x8 kf = *(const bf16x8*)(Ks + R * 64 + (((s * 4 + quad) ^ (R & 7)) << 3));
          sacc[t] = __builtin_amdgcn_mfma_f32_16x16x32_bf16(kf, qf1[s], sacc[t], 0, 0, 0);
        }
      if (kt == nkt - 1) {
#pragma unroll
        for (int t = 0; t < 4; t++)
#pragma unroll
          for (int r = 0; r < 4; r++)
            if (kt * 64 + t * 16 + quad * 4 + r > qrow1) sacc[t][r] = -1e30f;
      }
#pragma unroll
      for (int t = 0; t < 4; t++) {
        float p0 = __builtin_amdgcn_exp2f(sacc[t][0]);
        float p1 = __builtin_amdgcn_exp2f(sacc[t][1]);
        float p2 = __builtin_amdgcn_exp2f(sacc[t][2]);
        float p3 = __builtin_amdgcn_exp2f(sacc[t][3]);
        lsum1 += (p0 + p1) + (p2 + p3);
        uint2 pk;
        pk.x = (unsigned)f2bf(p0) | ((unsigned)f2bf(p1) << 16);
        pk.y = (unsigned)f2bf(p2) | ((unsigned)f2bf(p3) << 16);
        *(uint2*)(&Ps[wave][(16 + l16) * 72 + t * 16 + quad * 4]) = pk;
      }
    }
    // ---- frag0 S^T ----
    if (f0) {
      f32x4 sacc[4] = {};
#pragma unroll
      for (int s = 0; s < 2; s++)
#pragma unroll
        for (int t = 0; t < 4; t++) {
          const int R = t * 16 + l16;
          bf16x8 kf = *(const bf16x8*)(Ks + R * 64 + (((s * 4 + quad) ^ (R & 7)) << 3));
          sacc[t] = __builtin_amdgcn_mfma_f32_16x16x32_bf16(kf, qf0[s], sacc[t], 0, 0, 0);
        }
      if (kt == nkt - 2) {
#pragma unroll
        for (int t = 0; t < 4; t++)
#pragma unroll
          for (int r = 0; r < 4; r++)
            if (kt * 64 + t * 16 + quad * 4 + r > qrow0) sacc[t][r] = -1e30f;
      }
#pragma unroll
      for (int t = 0; t < 4; t++) {
        float p0 = __builtin_amdgcn_exp2f(sacc[t][0]);
        float p1 = __builtin_amdgcn_exp2f(sacc[t][1]);
        float p2 = __builtin_amdgcn_exp2f(sacc[t][2]);
        float p3 = __builtin_amdgcn_exp2f(sacc[t][3]);
        lsum0 += (p0 + p1) + (p2 + p3);
        uint2 pk;
        pk.x = (unsigned)f2bf(p0) | ((unsigned)f2bf(p1) << 16);
        pk.y = (unsigned)f2bf(p2) | ((unsigned)f2bf(p3) << 16);
        *(uint2*)(&Ps[wave][l16 * 72 + t * 16 + quad * 4]) = pk;
      }
    }
    // ---- PV ----
#pragma unroll
    for (int s = 0; s < 2; s++) {
      const bf16x8 pa1 = *(const bf16x8*)(&Ps[wave][(16 + l16) * 72 + s * 32 + quad * 8]);
#pragma unroll
      for (int t = 0; t < 4; t++) {
        const int R = t * 16 + l16;
        const bf16x8 vb = *(const bf16x8*)(Vt + R * 64 + (((s * 4 + quad) ^ (R & 7)) << 3));
        o1[t] = __builtin_amdgcn_mfma_f32_16x16x32_bf16(pa1, vb, o1[t], 0, 0, 0);
      }
    }
    if (f0) {
#pragma unroll
      for (int s = 0; s < 2; s++) {
        const bf16x8 pa0 = *(const bf16x8*)(&Ps[wave][l16 * 72 + s * 32 + quad * 8]);
#pragma unroll
        for (int t = 0; t < 4; t++) {
          const int R = t * 16 + l16;
          const bf16x8 vb = *(const bf16x8*)(Vt + R * 64 + (((s * 4 + quad) ^ (R & 7)) << 3));
          o0[t] = __builtin_amdgcn_mfma_f32_16x16x32_bf16(pa0, vb, o0[t], 0, 0, 0);
        }
      }
    }
  }
  // row-sum reduce over quads (q-row = l16)
  lsum0 += __shfl_xor(lsum0, 16);
  lsum0 += __shfl_xor(lsum0, 32);
  lsum1 += __shfl_xor(lsum1, 16);
  lsum1 += __shfl_xor(lsum1, 32);

  if (SPLIT) {
    // write unnormalized partials: o (f32) + per-row lsum
    const int pidx = (bh * 16 + qt2) * 2 + half;
    float* po = Po + (size_t)pidx * 8192;
#pragma unroll
    for (int t = 0; t < 4; t++)
#pragma unroll
      for (int r = 0; r < 4; r++) {
        const int row = wave * 16 + quad * 4 + r;
        po[row * 64 + t * 16 + l16] = o0[t][r];
        po[(row + 64) * 64 + t * 16 + l16] = o1[t][r];
      }
    if (lane < 16) {
      Pl[pidx * 128 + wave * 16 + l16] = lsum0;
      Pl[pidx * 128 + 64 + wave * 16 + l16] = lsum1;
    }
  } else {
    const float inv0 = 1.f / lsum0, inv1 = 1.f / lsum1;
    float invr0[4], invr1[4];
#pragma unroll
    for (int r = 0; r < 4; r++) {
      invr0[r] = __shfl(inv0, quad * 4 + r);
      invr1[r] = __shfl(inv1, quad * 4 + r);
    }
#pragma unroll
    for (int t = 0; t < 4; t++)
#pragma unroll
      for (int r = 0; r < 4; r++) {
        const int qg0 = qt2 * 128 + wave * 16 + quad * 4 + r;
        AO[((size_t)(b * 2048 + qg0) * 1024) + h * 64 + t * 16 + l16] =
            f2bf(o0[t][r] * invr0[r]);
        AO[((size_t)(b * 2048 + qg0 + 64) * 1024) + h * 64 + t * 16 + l16] =
            f2bf(o1[t][r] * invr1[r]);
      }
  }
}

// combine split-K partials: AO[row] = (o_a + o_b) / (lsum_a + lsum_b)
// 512 blocks (bh, qt2) x 256 threads (2 threads/row, 32 cols each)
__global__ __launch_bounds__(256) void combine_kernel(
    const float* __restrict__ Po, const float* __restrict__ Pl,
    uint16_t* __restrict__ AO) {
  const int cb = blockIdx.x;
  const int bh = cb >> 4, qt2 = cb & 15;
  const int b = bh >> 4, h = bh & 15;
  const int tid = threadIdx.x;
  const int row = tid >> 1;
  const int c0 = (tid & 1) * 32;
  const int p0 = (bh * 16 + qt2) * 2;
  const float inv = 1.f / (Pl[p0 * 128 + row] + Pl[(p0 + 1) * 128 + row]);
  const float* pa = Po + (size_t)p0 * 8192 + row * 64 + c0;
  const float* pb = pa + 8192;
  uint16_t* dst = AO + ((size_t)(b * 2048 + qt2 * 128 + row) * 1024) + h * 64 + c0;
#pragma unroll
  for (int i = 0; i < 4; i++) {
    const float4 a0 = ((const float4*)pa)[2 * i], a1 = ((const float4*)pa)[2 * i + 1];
    const float4 b0 = ((const float4*)pb)[2 * i], b1 = ((const float4*)pb)[2 * i + 1];
    bf16x8 v;
    v[0] = (__bf16)((a0.x + b0.x) * inv);
    v[1] = (__bf16)((a0.y + b0.y) * inv);
    v[2] = (__bf16)((a0.z + b0.z) * inv);
    v[3] = (__bf16)((a0.w + b0.w) * inv);
    v[4] = (__bf16)((a1.x + b1.x) * inv);
    v[5] = (__bf16)((a1.y + b1.y) * inv);
    v[6] = (__bf16)((a1.z + b1.z) * inv);
    v[7] = (__bf16)((a1.w + b1.w) * inv);
    *(bf16x8*)(dst + i * 8) = v;
  }
}

extern "C" void kernel_launch(void* const* d_in, const int* in_sizes, int n_in,
                              void* d_out, int out_size, void* d_ws, size_t ws_size,
                              hipStream_t stream) {
  const float* query = (const float*)d_in[0];
  const float* key   = (const float*)d_in[1];
  const float* value = (const float*)d_in[2];
  const float* Wq = (const float*)d_in[3];
  const float* bq = (const float*)d_in[4];
  const float* Wk = (const float*)d_in[5];
  const float* bk = (const float*)d_in[6];
  const float* Wv = (const float*)d_in[7];
  const float* bv = (const float*)d_in[8];
  const float* Wo = (const float*)d_in[9];
  const float* bo = (const float*)d_in[10];
  float* out = (float*)d_out;

  uint16_t* ws = (uint16_t*)d_ws;
  uint16_t* Qb  = ws;                         // [0,8M) bytes: bf16 (roped)
  uint16_t* Kb  = ws + (size_t)4194304;       // [8M,16M) (roped)
  uint16_t* VTb = ws + (size_t)8388608;       // [16M,24M) V^T [b,h,d,s]

  dim3 blk(256);

  if (ws_size >= (size_t)64 * 1024 * 1024) {
    // Fast path layout (fast-path lifetime analysis):
    //  [0,8M)    Qb (flash in) -> combine writes AO here (Qb dead by then)
    //  [8,16M)   Kb   [16,24M) VTb
    //  [24,24.5M)  Pl: split-K lsums (f32, 512 KB)
    //  [24.5,26.5M) Woc (bf16 Wo; alive until out-proj)
    //  [32,64M)  Qc/Kc/Vc/Wqc/Wkc/Wvc copies (dead after QKV gemm)
    //            -> reused as Po: split-K partial o (f32, 32 MB)
    float*    Pl  = (float*)(ws + (size_t)12582912);   // byte 24M
    uint16_t* Woc = ws + (size_t)12845056;             // byte 24.5M
    uint16_t* Qc  = ws + (size_t)16777216;             // byte 32M
    uint16_t* Kc  = ws + (size_t)20971520;             // byte 40M
    uint16_t* Vc  = ws + (size_t)25165824;             // byte 48M
    uint16_t* Wqc = ws + (size_t)29360128;             // byte 56M
    uint16_t* Wkc = ws + (size_t)30408704;             // byte 58M
    uint16_t* Wvc = ws + (size_t)31457280;             // byte 60M
    float*    Po  = (float*)(ws + (size_t)16777216);   // byte 32M, 32 MB
    uint16_t* AOc = ws;                                 // over Qb

    cvt_kernel<<<dim3(512, 1, 4), blk, 0, stream>>>(
        Wq, Wqc, Wk, Wkc, Wv, Wvc, Wo, Woc);
    cvt_kernel<<<dim3(2048, 1, 3), blk, 0, stream>>>(
        query, Qc, key, Kc, value, Vc, nullptr, nullptr);
    // QKV: pure bf16, 128x128 tile, both operands global_load_lds
    gemm3_kernel<false, false, false, true, true, 128, 4><<<dim3(8, 32, 3), blk, 0, stream>>>(
        Qc, Wqc, bq, Qb,
        Kc, Wkc, bk, Kb,
        Vc, Wvc, bv, VTb,
        4096, 1024, 1024);
    // split-K flash: 1024 blocks = 4/CU, partials to Po/Pl
    flash_kernel<true><<<dim3(1024), blk, 0, stream>>>(Qb, Kb, VTb, nullptr, Po, Pl);
    combine_kernel<<<dim3(512), blk, 0, stream>>>(Po, Pl, AOc);
    // out-proj: pure bf16 128x64, both DMA; A = combined attention out
    gemm3_kernel<false, false, true, false, false, 128, 2><<<dim3(16, 32, 1), blk, 0, stream>>>(
        AOc, Woc, bo, out,
        AOc, Woc, bo, out,
        AOc, Woc, bo, out,
        4096, 1024, 1024);
  } else {
    // Fallback: R0 GEMM configuration + R8 flash (32MB workspace).
    uint16_t* AOb = ws + (size_t)12582912;
    uint16_t* Wqc = AOb;
    uint16_t* Wkc = AOb + (size_t)1048576;
    uint16_t* Wvc = AOb + (size_t)2097152;
    cvt_kernel<<<dim3(512, 1, 3), blk, 0, stream>>>(
        Wq, Wqc, Wk, Wkc, Wv, Wvc, nullptr, nullptr);
    gemm3_kernel<true, false, false, true, true, 128, 2><<<dim3(16, 32, 3), blk, 0, stream>>>(
        query, Wqc, bq, Qb,
        key,   Wkc, bk, Kb,
        value, Wvc, bv, VTb,
        4096, 1024, 1024);
    flash_kernel<false><<<dim3(512), blk, 0, stream>>>(Qb, Kb, VTb, AOb, nullptr, nullptr);
    gemm3_kernel<false, true, true, false, false, 128, 2><<<dim3(16, 32, 1), blk, 0, stream>>>(
        AOb, Wo, bo, out,
        AOb, Wo, bo, out,
        AOb, Wo, bo, out,
        4096, 1024, 1024);
  }
}